// Round 2
// baseline (328.991 us; speedup 1.0000x reference)
//
#include <hip/hip_runtime.h>

#define N_RELS 16
#define N_BASES 8
#define HD 128
#define SCAN_B 1024
#define ROWS 32

typedef __attribute__((ext_vector_type(8))) short bf16x8;
typedef __attribute__((ext_vector_type(4))) float floatx4;
typedef __attribute__((ext_vector_type(2))) float floatx2;

__device__ __forceinline__ short bf16rn(float f) {
    union { float f; unsigned u; } v; v.f = f;
    unsigned u = v.u;
    unsigned r = (u + 0x7fffu + ((u >> 16) & 1u)) >> 16;
    return (short)r;
}

// ---------------- fused setup: pack h->bf16 | V->frags | dst histogram ----------------

__global__ void setup_fused(const float* __restrict__ h, unsigned* __restrict__ hb, int n4,
                            const float* __restrict__ V1, const float* __restrict__ V2,
                            short* __restrict__ Vf,
                            const int* __restrict__ dst, int E, int* __restrict__ cnt,
                            int packBlocks, int vBlocks) {
    int blk = blockIdx.x;
    if (blk < packBlocks) {
        int i = blk * blockDim.x + threadIdx.x;
        if (i < n4) {
            float4 v = ((const float4*)h)[i];
            uint2 o;
            o.x = ((unsigned)(unsigned short)bf16rn(v.y) << 16) | (unsigned short)bf16rn(v.x);
            o.y = ((unsigned)(unsigned short)bf16rn(v.w) << 16) | (unsigned short)bf16rn(v.z);
            ((uint2*)hb)[i] = o;
        }
        return;
    }
    blk -= packBlocks;
    if (blk < vBlocks) {
        // frag: lane holds B[n=lane&15][k=(lane>>4)*8+j]; idx = ((kk*8+t)*64+lane)*8+j
        const float* V = ((blk & 8) ? V2 : V1) + (size_t)(blk & 7) * 16384;
        size_t obase = (size_t)blk * 16384;
        for (int e = threadIdx.x; e < 16384; e += blockDim.x) {
            float w = V[e];
            int k = e >> 7, n = e & 127;
            int kk = k >> 5, q = (k >> 3) & 3, j = k & 7;
            int lane = q * 16 + (n & 15);
            int idx = ((kk * 8 + (n >> 4)) * 64 + lane) * 8 + j;
            Vf[obase + idx] = bf16rn(w);
        }
        return;
    }
    blk -= vBlocks;
    int i = blk * blockDim.x + threadIdx.x;
    if (i < E) atomicAdd(&cnt[dst[i]], 1);
}

// ---------------- counting-sort scan (2 kernels) ----------------

__global__ void scan_partial(const int* __restrict__ cnt, int N,
                             int* __restrict__ excl, int* __restrict__ bsum) {
    __shared__ int s[SCAN_B];
    int t = threadIdx.x, i = blockIdx.x * SCAN_B + t;
    int v = (i < N) ? cnt[i] : 0;
    s[t] = v; __syncthreads();
    for (int o = 1; o < SCAN_B; o <<= 1) {
        int x = (t >= o) ? s[t - o] : 0;
        __syncthreads();
        s[t] += x;
        __syncthreads();
    }
    if (i < N) excl[i] = s[t] - v;
    if (t == SCAN_B - 1) bsum[blockIdx.x] = s[t];
}

// adds block-sum prefix (computed in-wave, nb<=64) and inits cursor
__global__ void scan_fixup(int* __restrict__ row_ptr, const int* __restrict__ bsum,
                           int nb, int N, int E, int* __restrict__ cursor) {
    __shared__ int pref[64];
    int t = threadIdx.x;
    if (t < 64) {
        int raw = (t < nb) ? bsum[t] : 0;
        int v = raw;
#pragma unroll
        for (int o = 1; o < 64; o <<= 1) {
            int u = __shfl_up(v, o, 64);
            if (t >= o) v += u;
        }
        pref[t] = v - raw;     // exclusive prefix
    }
    __syncthreads();
    int i = blockIdx.x * blockDim.x + t;
    if (i < N) { int val = row_ptr[i] + pref[i >> 10]; row_ptr[i] = val; cursor[i] = val; }
    if (i == 0) row_ptr[N] = E;
}

// pack (etype, src) into one int: src < 65536
__global__ void scatter_dst(const int* __restrict__ dst, const int* __restrict__ src,
                            const int* __restrict__ et, const float* __restrict__ norm,
                            int E, int* __restrict__ cursor, int2* __restrict__ edata) {
    int i = blockIdx.x * blockDim.x + threadIdx.x;
    if (i >= E) return;
    int p = atomicAdd(&cursor[dst[i]], 1);
    edata[p] = make_int2((et[i] << 16) | src[i], __float_as_int(norm[i]));
}

// ---------------- fused per-tile RGCN layer ----------------
// Block = 32 dst rows, 512 threads (8 waves). Phase A: wave w owns rows [4w,4w+4) whose
// edata ranges are CONTIGUOUS (counting-sorted by dst) -> flatten into one edge stream,
// groups of 8 gathers in flight, next group's edata prefetched (edata never on the
// dependent chain). Row crossings detected with wave-uniform scalar compares; acc is
// flushed to the Z tile in LDS (MFMA A-frag order, m padded 32->33). Same per-row edge
// order as baseline -> bit-identical accumulation.
// Phase B: Z(32x1024) @ V(1024x128); B-frags from L2-resident Vf; wave = t-tile x 2 m.
// mode 0: store bf16(relu(acc+bias)); mode 1: store fp32(acc+bias).

__global__ __launch_bounds__(512, 4) void rgcn_tile(
    const unsigned* __restrict__ hb, const int2* __restrict__ edata,
    const int* __restrict__ row_ptr, const float* __restrict__ coef,
    const short* __restrict__ Vf, const float* __restrict__ bias,
    void* __restrict__ outp, int N, int E, int mode) {
    __shared__ __align__(16) unsigned Zs[N_BASES][4][4][ROWS + 1][4];  // 66 KB

    const int tid = threadIdx.x;
    const int wave = tid >> 6, lane = tid & 63;
    const int nb0 = blockIdx.x * ROWS;

    // phase-A frag coords: lane covers cols 2*lane, 2*lane+1
    const int lkk = lane >> 4, lq = (lane >> 2) & 3, lju = lane & 3;

    // wave's 4 rows: local rows r0..r0+3; boundaries in the edge stream (wave-uniform)
    const int r0 = wave * 4;
    int bounds[5];
#pragma unroll
    for (int i = 0; i < 5; i++) {
        int nd = nb0 + r0 + i; if (nd > N) nd = N;
        bounds[i] = __builtin_amdgcn_readfirstlane(row_ptr[nd]);
    }
    int e = bounds[0];
    const int eend = bounds[4];

    floatx2 acc[N_BASES] = {};
    int cur = 0;

    auto proc = [&](int2 m, unsigned g) {
        int ets = __builtin_amdgcn_readfirstlane(m.x >> 16);   // et wave-uniform
        float nv = __int_as_float(m.y);
        const float* cw = coef + ets * N_BASES;                // scalar loads
        floatx2 v;
        v.x = __uint_as_float(g << 16) * nv;
        v.y = __uint_as_float(g & 0xffff0000u) * nv;
#pragma unroll
        for (int b = 0; b < N_BASES; b++)
            acc[b] = v * cw[b] + acc[b];                       // v_pk_fma_f32
    };
    auto flush = [&](int r) {
#pragma unroll
        for (int b = 0; b < N_BASES; b++) {
            unsigned lo = (unsigned)(unsigned short)bf16rn(acc[b].x);
            unsigned hi = (unsigned)(unsigned short)bf16rn(acc[b].y);
            Zs[b][lkk][lq][r0 + r][lju] = (hi << 16) | lo;
            acc[b].x = 0.f; acc[b].y = 0.f;
        }
    };

    // prime the edata pipeline (clamped index: always a valid address, unused lanes ignored)
    int2 mb[8];
#pragma unroll
    for (int j = 0; j < 8; j++) { int ix = e + j; if (ix > E - 1) ix = E - 1; mb[j] = edata[ix]; }

    while (e + 8 <= eend) {
        unsigned g[8];
#pragma unroll
        for (int j = 0; j < 8; j++) g[j] = hb[(size_t)(mb[j].x & 0xffff) * 64 + lane];
        int2 nxt[8];
#pragma unroll
        for (int j = 0; j < 8; j++) { int ix = e + 8 + j; if (ix > E - 1) ix = E - 1; nxt[j] = edata[ix]; }
#pragma unroll
        for (int j = 0; j < 8; j++) {
            while (cur < 3 && e + j >= bounds[cur + 1]) { flush(cur); cur++; }
            proc(mb[j], g[j]);
        }
#pragma unroll
        for (int j = 0; j < 8; j++) mb[j] = nxt[j];
        e += 8;
    }
    {
        const int rem = eend - e;   // 0..7, wave-uniform
        unsigned g[8];
#pragma unroll
        for (int j = 0; j < 8; j++)
            if (j < rem) g[j] = hb[(size_t)(mb[j].x & 0xffff) * 64 + lane];
#pragma unroll
        for (int j = 0; j < 8; j++)
            if (j < rem) {
                while (cur < 3 && e + j >= bounds[cur + 1]) { flush(cur); cur++; }
                proc(mb[j], g[j]);
            }
    }
    while (cur < 4) { flush(cur); cur++; }   // remaining rows (incl. empty / node>=N: zeros)

    __syncthreads();

    // ---- phase B: wave owns t-tile tt=wave, m-tiles {0,1}
    const int q = lane >> 4, cc = lane & 15;
    const int tt = wave;
    floatx4 ac0 = {}, ac1 = {};

#pragma unroll 2
    for (int b = 0; b < N_BASES; b++) {
#pragma unroll
        for (int kk = 0; kk < 4; kk++) {
            bf16x8 a0 = *(const bf16x8*)&Zs[b][kk][q][cc][0];
            bf16x8 a1 = *(const bf16x8*)&Zs[b][kk][q][16 + cc][0];
            bf16x8 B = *(const bf16x8*)(Vf + (size_t)b * 16384 +
                                        ((size_t)(kk * 8 + tt) * 64 + lane) * 8);
            ac0 = __builtin_amdgcn_mfma_f32_16x16x32_bf16(a0, B, ac0, 0, 0, 0);
            ac1 = __builtin_amdgcn_mfma_f32_16x16x32_bf16(a1, B, ac1, 0, 0, 0);
        }
    }

    // ---- epilogue: C/D layout col = tt*16+cc, row(m) = mi*16 + q*4+i
    float bv = bias[tt * 16 + cc];
    if (mode == 0) {
        unsigned short* o = (unsigned short*)outp;
#pragma unroll
        for (int mi = 0; mi < 2; mi++) {
            const floatx4& c = mi ? ac1 : ac0;
#pragma unroll
            for (int i = 0; i < 4; i++) {
                int node = nb0 + mi * 16 + q * 4 + i;
                if (node < N) {
                    float v = fmaxf(c[i] + bv, 0.f);
                    o[(size_t)node * HD + tt * 16 + cc] = (unsigned short)bf16rn(v);
                }
            }
        }
    } else {
        float* o = (float*)outp;
#pragma unroll
        for (int mi = 0; mi < 2; mi++) {
            const floatx4& c = mi ? ac1 : ac0;
#pragma unroll
            for (int i = 0; i < 4; i++) {
                int node = nb0 + mi * 16 + q * 4 + i;
                if (node < N) o[(size_t)node * HD + tt * 16 + cc] = c[i] + bv;
            }
        }
    }
}

// ---------------- launch ----------------

extern "C" void kernel_launch(void* const* d_in, const int* in_sizes, int n_in,
                              void* d_out, int out_size, void* d_ws, size_t ws_size,
                              hipStream_t stream) {
    const float* h     = (const float*)d_in[0];
    const float* norm  = (const float*)d_in[1];
    const int*   src   = (const int*)d_in[2];
    const int*   dst   = (const int*)d_in[3];
    const int*   etype = (const int*)d_in[4];
    const float* V1    = (const float*)d_in[5];
    const float* coef1 = (const float*)d_in[6];
    const float* bias1 = (const float*)d_in[7];
    const float* V2    = (const float*)d_in[8];
    const float* coef2 = (const float*)d_in[9];
    const float* bias2 = (const float*)d_in[10];
    const int N = in_sizes[0] / HD;   // 50000
    const int E = in_sizes[2];        // 640000
    float* out = (float*)d_out;
    (void)n_in; (void)out_size; (void)ws_size;

    char* ws = (char*)d_ws;
    size_t off = 0;
    auto alloc = [&](size_t bytes) {
        void* p = ws + off;
        off += (bytes + 255) & ~(size_t)255;
        return p;
    };
    short*    Vf      = (short*)alloc((size_t)16 * 16384 * sizeof(short));   // 512 KB
    unsigned* hb      = (unsigned*)alloc((size_t)N * 64 * sizeof(unsigned)); // 12.8 MB
    unsigned* h1b     = (unsigned*)alloc((size_t)N * 64 * sizeof(unsigned)); // 12.8 MB
    int2*     edata   = (int2*)alloc((size_t)E * sizeof(int2));
    int*      cnt     = (int*)alloc((size_t)N * sizeof(int));
    int*      row_ptr = (int*)alloc((size_t)(N + 1) * sizeof(int));
    int*      cursor  = (int*)alloc((size_t)N * sizeof(int));
    int*      bsum    = (int*)alloc(256 * sizeof(int));

    const int nb = (N + SCAN_B - 1) / SCAN_B;                 // 49
    const int packBlocks = (N * 32 + 255) / 256;              // 6250 (float4 pack)
    const int vBlocks = 16;
    const int histBlocks = (E + 255) / 256;                   // 2500

    hipMemsetAsync(cnt, 0, (size_t)N * sizeof(int), stream);
    setup_fused<<<packBlocks + vBlocks + histBlocks, 256, 0, stream>>>(
        h, hb, N * 32, V1, V2, Vf, dst, E, cnt, packBlocks, vBlocks);
    scan_partial<<<nb, SCAN_B, 0, stream>>>(cnt, N, row_ptr, bsum);
    scan_fixup<<<(N + 255) / 256, 256, 0, stream>>>(row_ptr, bsum, nb, N, E, cursor);
    scatter_dst<<<(E + 255) / 256, 256, 0, stream>>>(dst, src, etype, norm, E, cursor, edata);

    const int tiles = (N + ROWS - 1) / ROWS;   // 1563

    // layer 1: h1b = bf16(relu(bias1 + Z @ V1))
    rgcn_tile<<<tiles, 512, 0, stream>>>(hb, edata, row_ptr, coef1, Vf, bias1, h1b, N, E, 0);
    // layer 2: out = bias2 + Z(h1b) @ V2
    rgcn_tile<<<tiles, 512, 0, stream>>>(h1b, edata, row_ptr, coef2, Vf + (size_t)8 * 16384,
                                         bias2, out, N, E, 1);
}

// Round 3
// 325.728 us; speedup vs baseline: 1.0100x; 1.0100x over previous
//
#include <hip/hip_runtime.h>

#define N_RELS 16
#define N_BASES 8
#define HD 128
#define SCAN_B 1024
#define ROWS 32

typedef __attribute__((ext_vector_type(8))) short bf16x8;
typedef __attribute__((ext_vector_type(4))) float floatx4;
typedef __attribute__((ext_vector_type(2))) float floatx2;

__device__ __forceinline__ short bf16rn(float f) {
    union { float f; unsigned u; } v; v.f = f;
    unsigned u = v.u;
    unsigned r = (u + 0x7fffu + ((u >> 16) & 1u)) >> 16;
    return (short)r;
}

// ---------------- fused setup: pack h->bf16 | V->frags | dst histogram ----------------

__global__ void setup_fused(const float* __restrict__ h, unsigned* __restrict__ hb, int n4,
                            const float* __restrict__ V1, const float* __restrict__ V2,
                            short* __restrict__ Vf,
                            const int* __restrict__ dst, int E, int* __restrict__ cnt,
                            int packBlocks, int vBlocks) {
    int blk = blockIdx.x;
    if (blk < packBlocks) {
        int i = blk * blockDim.x + threadIdx.x;
        if (i < n4) {
            float4 v = ((const float4*)h)[i];
            uint2 o;
            o.x = ((unsigned)(unsigned short)bf16rn(v.y) << 16) | (unsigned short)bf16rn(v.x);
            o.y = ((unsigned)(unsigned short)bf16rn(v.w) << 16) | (unsigned short)bf16rn(v.z);
            ((uint2*)hb)[i] = o;
        }
        return;
    }
    blk -= packBlocks;
    if (blk < vBlocks) {
        // frag: lane holds B[n=lane&15][k=(lane>>4)*8+j]; idx = ((kk*8+t)*64+lane)*8+j
        const float* V = ((blk & 8) ? V2 : V1) + (size_t)(blk & 7) * 16384;
        size_t obase = (size_t)blk * 16384;
        for (int e = threadIdx.x; e < 16384; e += blockDim.x) {
            float w = V[e];
            int k = e >> 7, n = e & 127;
            int kk = k >> 5, q = (k >> 3) & 3, j = k & 7;
            int lane = q * 16 + (n & 15);
            int idx = ((kk * 8 + (n >> 4)) * 64 + lane) * 8 + j;
            Vf[obase + idx] = bf16rn(w);
        }
        return;
    }
    blk -= vBlocks;
    int i = blk * blockDim.x + threadIdx.x;
    if (i < E) atomicAdd(&cnt[dst[i]], 1);
}

// ---------------- counting-sort scan (2 kernels) ----------------

__global__ void scan_partial(const int* __restrict__ cnt, int N,
                             int* __restrict__ excl, int* __restrict__ bsum) {
    __shared__ int s[SCAN_B];
    int t = threadIdx.x, i = blockIdx.x * SCAN_B + t;
    int v = (i < N) ? cnt[i] : 0;
    s[t] = v; __syncthreads();
    for (int o = 1; o < SCAN_B; o <<= 1) {
        int x = (t >= o) ? s[t - o] : 0;
        __syncthreads();
        s[t] += x;
        __syncthreads();
    }
    if (i < N) excl[i] = s[t] - v;
    if (t == SCAN_B - 1) bsum[blockIdx.x] = s[t];
}

// adds block-sum prefix (computed in-wave, nb<=64) and inits cursor
__global__ void scan_fixup(int* __restrict__ row_ptr, const int* __restrict__ bsum,
                           int nb, int N, int E, int* __restrict__ cursor) {
    __shared__ int pref[64];
    int t = threadIdx.x;
    if (t < 64) {
        int raw = (t < nb) ? bsum[t] : 0;
        int v = raw;
#pragma unroll
        for (int o = 1; o < 64; o <<= 1) {
            int u = __shfl_up(v, o, 64);
            if (t >= o) v += u;
        }
        pref[t] = v - raw;     // exclusive prefix
    }
    __syncthreads();
    int i = blockIdx.x * blockDim.x + t;
    if (i < N) { int val = row_ptr[i] + pref[i >> 10]; row_ptr[i] = val; cursor[i] = val; }
    if (i == 0) row_ptr[N] = E;
}

// pack (etype, src) into one int: src < 65536
__global__ void scatter_dst(const int* __restrict__ dst, const int* __restrict__ src,
                            const int* __restrict__ et, const float* __restrict__ norm,
                            int E, int* __restrict__ cursor, int2* __restrict__ edata) {
    int i = blockIdx.x * blockDim.x + threadIdx.x;
    if (i >= E) return;
    int p = atomicAdd(&cursor[dst[i]], 1);
    edata[p] = make_int2((et[i] << 16) | src[i], __float_as_int(norm[i]));
}

// ---------------- fused per-tile RGCN layer ----------------
// Block = 32 dst rows, 512 threads (8 waves). Phase A: wave w owns rows [4w,4w+4)
// (edata ranges contiguous via counting sort) -> one flat edge stream per wave,
// processed in groups of 8 with a 3-stage rotating pipeline:
//   loadM(m[i+2]) ; issueG(g[i+1] from m[i+1]) ; procG(m[i], g[i])
// edata for i+2 is issued BEFORE gathers of i+1, so every wait is a counted
// vmcnt(~16) -- the vector-memory FIFO never drains (round-2 failure mode was a
// register copy forcing vmcnt(0)/iter). Row crossings via wave-uniform compares;
// acc flushed to Z tile in LDS (MFMA A-frag order, m padded 32->33). Same per-row
// edge order as baseline -> identical accumulation.
// Phase B: Z(32x1024) @ V(1024x128); B-frags from L2-resident Vf; wave = t-tile x 2 m.
// mode 0: store bf16(relu(acc+bias)); mode 1: store fp32(acc+bias).

__global__ __launch_bounds__(512, 4) void rgcn_tile(
    const unsigned* __restrict__ hb, const int2* __restrict__ edata,
    const int* __restrict__ row_ptr, const float* __restrict__ coef,
    const short* __restrict__ Vf, const float* __restrict__ bias,
    void* __restrict__ outp, int N, int E, int mode) {
    __shared__ __align__(16) unsigned Zs[N_BASES][4][4][ROWS + 1][4];  // 66 KB

    const int tid = threadIdx.x;
    const int wave = tid >> 6, lane = tid & 63;
    const int nb0 = blockIdx.x * ROWS;

    // phase-A frag coords: lane covers cols 2*lane, 2*lane+1
    const int lkk = lane >> 4, lq = (lane >> 2) & 3, lju = lane & 3;

    // wave's 4 rows: local rows r0..r0+3; boundaries in the edge stream (wave-uniform)
    const int r0 = wave * 4;
    int bounds[5];
#pragma unroll
    for (int i = 0; i < 5; i++) {
        int nd = nb0 + r0 + i; if (nd > N) nd = N;
        bounds[i] = __builtin_amdgcn_readfirstlane(row_ptr[nd]);
    }
    const int e0 = bounds[0];
    const int eend = bounds[4];
    const int nG = (eend - e0 + 7) >> 3;   // groups of 8, wave-uniform

    floatx2 acc[N_BASES] = {};
    int cur = 0;

    auto proc = [&](int2 m, unsigned g) {
        int ets = __builtin_amdgcn_readfirstlane(m.x >> 16);   // et wave-uniform
        float nv = __int_as_float(m.y);
        const float* cw = coef + ets * N_BASES;                // scalar loads
        floatx2 v;
        v.x = __uint_as_float(g << 16) * nv;
        v.y = __uint_as_float(g & 0xffff0000u) * nv;
#pragma unroll
        for (int b = 0; b < N_BASES; b++)
            acc[b] = v * cw[b] + acc[b];                       // v_pk_fma_f32
    };
    auto flush = [&](int r) {
#pragma unroll
        for (int b = 0; b < N_BASES; b++) {
            unsigned lo = (unsigned)(unsigned short)bf16rn(acc[b].x);
            unsigned hi = (unsigned)(unsigned short)bf16rn(acc[b].y);
            Zs[b][lkk][lq][r0 + r][lju] = (hi << 16) | lo;
            acc[b].x = 0.f; acc[b].y = 0.f;
        }
    };
    auto loadM = [&](int2* mb, int base) {     // base wave-uniform; clamped -> always valid
#pragma unroll
        for (int j = 0; j < 8; j++) {
            int ix = base + j; if (ix > E - 1) ix = E - 1;
            mb[j] = edata[ix];
        }
    };
    auto issueG = [&](unsigned* gb, const int2* mb) {
#pragma unroll
        for (int j = 0; j < 8; j++)
            gb[j] = hb[(size_t)(mb[j].x & 0xffff) * 64 + lane];
    };
    auto procG = [&](const int2* mb, const unsigned* gb, int bb) {
        int lim = eend - bb; if (lim > 8) lim = 8;             // wave-uniform
#pragma unroll
        for (int j = 0; j < 8; j++)
            if (j < lim) {
                while (cur < 3 && bb + j >= bounds[cur + 1]) { flush(cur); cur++; }
                proc(mb[j], gb[j]);
            }
    };

    int2 m0[8], m1[8], m2[8];
    unsigned g0[8], g1[8], g2[8];

    // prologue: group0 gathers in flight, group1 edata in flight
    loadM(m0, e0);
    issueG(g0, m0);
    loadM(m1, e0 + 8);

    int k = 0, base = e0;
    for (; k + 3 <= nG; k += 3, base += 24) {
        loadM(m2, base + 16); issueG(g1, m1); procG(m0, g0, base);
        loadM(m0, base + 24); issueG(g2, m2); procG(m1, g1, base + 8);
        loadM(m1, base + 32); issueG(g0, m0); procG(m2, g2, base + 16);
    }
    // tail: at most 2 groups; g0 in flight for group k, m1 holds group k+1
    if (k < nG) {
        if (k + 1 < nG) issueG(g1, m1);
        procG(m0, g0, base);
        if (k + 1 < nG) procG(m1, g1, base + 8);
    }
    while (cur < 4) { flush(cur); cur++; }   // remaining rows (incl. empty / node>=N: zeros)

    __syncthreads();

    // ---- phase B: wave owns t-tile tt=wave, m-tiles {0,1}
    const int q = lane >> 4, cc = lane & 15;
    const int tt = wave;
    floatx4 ac0 = {}, ac1 = {};

#pragma unroll 2
    for (int b = 0; b < N_BASES; b++) {
#pragma unroll
        for (int kk = 0; kk < 4; kk++) {
            bf16x8 a0 = *(const bf16x8*)&Zs[b][kk][q][cc][0];
            bf16x8 a1 = *(const bf16x8*)&Zs[b][kk][q][16 + cc][0];
            bf16x8 B = *(const bf16x8*)(Vf + (size_t)b * 16384 +
                                        ((size_t)(kk * 8 + tt) * 64 + lane) * 8);
            ac0 = __builtin_amdgcn_mfma_f32_16x16x32_bf16(a0, B, ac0, 0, 0, 0);
            ac1 = __builtin_amdgcn_mfma_f32_16x16x32_bf16(a1, B, ac1, 0, 0, 0);
        }
    }

    // ---- epilogue: C/D layout col = tt*16+cc, row(m) = mi*16 + q*4+i
    float bv = bias[tt * 16 + cc];
    if (mode == 0) {
        unsigned short* o = (unsigned short*)outp;
#pragma unroll
        for (int mi = 0; mi < 2; mi++) {
            const floatx4& c = mi ? ac1 : ac0;
#pragma unroll
            for (int i = 0; i < 4; i++) {
                int node = nb0 + mi * 16 + q * 4 + i;
                if (node < N) {
                    float v = fmaxf(c[i] + bv, 0.f);
                    o[(size_t)node * HD + tt * 16 + cc] = (unsigned short)bf16rn(v);
                }
            }
        }
    } else {
        float* o = (float*)outp;
#pragma unroll
        for (int mi = 0; mi < 2; mi++) {
            const floatx4& c = mi ? ac1 : ac0;
#pragma unroll
            for (int i = 0; i < 4; i++) {
                int node = nb0 + mi * 16 + q * 4 + i;
                if (node < N) o[(size_t)node * HD + tt * 16 + cc] = c[i] + bv;
            }
        }
    }
}

// ---------------- launch ----------------

extern "C" void kernel_launch(void* const* d_in, const int* in_sizes, int n_in,
                              void* d_out, int out_size, void* d_ws, size_t ws_size,
                              hipStream_t stream) {
    const float* h     = (const float*)d_in[0];
    const float* norm  = (const float*)d_in[1];
    const int*   src   = (const int*)d_in[2];
    const int*   dst   = (const int*)d_in[3];
    const int*   etype = (const int*)d_in[4];
    const float* V1    = (const float*)d_in[5];
    const float* coef1 = (const float*)d_in[6];
    const float* bias1 = (const float*)d_in[7];
    const float* V2    = (const float*)d_in[8];
    const float* coef2 = (const float*)d_in[9];
    const float* bias2 = (const float*)d_in[10];
    const int N = in_sizes[0] / HD;   // 50000
    const int E = in_sizes[2];        // 640000
    float* out = (float*)d_out;
    (void)n_in; (void)out_size; (void)ws_size;

    char* ws = (char*)d_ws;
    size_t off = 0;
    auto alloc = [&](size_t bytes) {
        void* p = ws + off;
        off += (bytes + 255) & ~(size_t)255;
        return p;
    };
    short*    Vf      = (short*)alloc((size_t)16 * 16384 * sizeof(short));   // 512 KB
    unsigned* hb      = (unsigned*)alloc((size_t)N * 64 * sizeof(unsigned)); // 12.8 MB
    unsigned* h1b     = (unsigned*)alloc((size_t)N * 64 * sizeof(unsigned)); // 12.8 MB
    int2*     edata   = (int2*)alloc((size_t)E * sizeof(int2));
    int*      cnt     = (int*)alloc((size_t)N * sizeof(int));
    int*      row_ptr = (int*)alloc((size_t)(N + 1) * sizeof(int));
    int*      cursor  = (int*)alloc((size_t)N * sizeof(int));
    int*      bsum    = (int*)alloc(256 * sizeof(int));

    const int nb = (N + SCAN_B - 1) / SCAN_B;                 // 49
    const int packBlocks = (N * 32 + 255) / 256;              // 6250 (float4 pack)
    const int vBlocks = 16;
    const int histBlocks = (E + 255) / 256;                   // 2500

    hipMemsetAsync(cnt, 0, (size_t)N * sizeof(int), stream);
    setup_fused<<<packBlocks + vBlocks + histBlocks, 256, 0, stream>>>(
        h, hb, N * 32, V1, V2, Vf, dst, E, cnt, packBlocks, vBlocks);
    scan_partial<<<nb, SCAN_B, 0, stream>>>(cnt, N, row_ptr, bsum);
    scan_fixup<<<(N + 255) / 256, 256, 0, stream>>>(row_ptr, bsum, nb, N, E, cursor);
    scatter_dst<<<(E + 255) / 256, 256, 0, stream>>>(dst, src, etype, norm, E, cursor, edata);

    const int tiles = (N + ROWS - 1) / ROWS;   // 1563

    // layer 1: h1b = bf16(relu(bias1 + Z @ V1))
    rgcn_tile<<<tiles, 512, 0, stream>>>(hb, edata, row_ptr, coef1, Vf, bias1, h1b, N, E, 0);
    // layer 2: out = bias2 + Z(h1b) @ V2
    rgcn_tile<<<tiles, 512, 0, stream>>>(h1b, edata, row_ptr, coef2, Vf + (size_t)8 * 16384,
                                         bias2, out, N, E, 1);
}

// Round 4
// 304.584 us; speedup vs baseline: 1.0801x; 1.0694x over previous
//
#include <hip/hip_runtime.h>

#define N_RELS 16
#define N_BASES 8
#define HD 128
#define SCAN_B 1024
#define ROWS 32

typedef __attribute__((ext_vector_type(8))) short bf16x8;
typedef __attribute__((ext_vector_type(4))) float floatx4;
typedef __attribute__((ext_vector_type(2))) float floatx2;

__device__ __forceinline__ short bf16rn(float f) {
    union { float f; unsigned u; } v; v.f = f;
    unsigned u = v.u;
    unsigned r = (u + 0x7fffu + ((u >> 16) & 1u)) >> 16;
    return (short)r;
}

__device__ __forceinline__ unsigned packbf2(floatx2 a) {
    return ((unsigned)(unsigned short)bf16rn(a.y) << 16) | (unsigned short)bf16rn(a.x);
}

// ---------------- fused setup: pack h->bf16 | V->frags | dst histogram ----------------

__global__ void setup_fused(const float* __restrict__ h, unsigned* __restrict__ hb, int n4,
                            const float* __restrict__ V1, const float* __restrict__ V2,
                            short* __restrict__ Vf,
                            const int* __restrict__ dst, int E, int* __restrict__ cnt,
                            int packBlocks, int vBlocks) {
    int blk = blockIdx.x;
    if (blk < packBlocks) {
        int i = blk * blockDim.x + threadIdx.x;
        if (i < n4) {
            float4 v = ((const float4*)h)[i];
            uint2 o;
            o.x = ((unsigned)(unsigned short)bf16rn(v.y) << 16) | (unsigned short)bf16rn(v.x);
            o.y = ((unsigned)(unsigned short)bf16rn(v.w) << 16) | (unsigned short)bf16rn(v.z);
            ((uint2*)hb)[i] = o;
        }
        return;
    }
    blk -= packBlocks;
    if (blk < vBlocks) {
        // frag: lane holds B[n=lane&15][k=(lane>>4)*8+j]; idx = ((kk*8+t)*64+lane)*8+j
        const float* V = ((blk & 8) ? V2 : V1) + (size_t)(blk & 7) * 16384;
        size_t obase = (size_t)blk * 16384;
        for (int e = threadIdx.x; e < 16384; e += blockDim.x) {
            float w = V[e];
            int k = e >> 7, n = e & 127;
            int kk = k >> 5, q = (k >> 3) & 3, j = k & 7;
            int lane = q * 16 + (n & 15);
            int idx = ((kk * 8 + (n >> 4)) * 64 + lane) * 8 + j;
            Vf[obase + idx] = bf16rn(w);
        }
        return;
    }
    blk -= vBlocks;
    int i = blk * blockDim.x + threadIdx.x;
    if (i < E) atomicAdd(&cnt[dst[i]], 1);
}

// ---------------- counting-sort scan (2 kernels) ----------------

__global__ void scan_partial(const int* __restrict__ cnt, int N,
                             int* __restrict__ excl, int* __restrict__ bsum) {
    __shared__ int s[SCAN_B];
    int t = threadIdx.x, i = blockIdx.x * SCAN_B + t;
    int v = (i < N) ? cnt[i] : 0;
    s[t] = v; __syncthreads();
    for (int o = 1; o < SCAN_B; o <<= 1) {
        int x = (t >= o) ? s[t - o] : 0;
        __syncthreads();
        s[t] += x;
        __syncthreads();
    }
    if (i < N) excl[i] = s[t] - v;
    if (t == SCAN_B - 1) bsum[blockIdx.x] = s[t];
}

// adds block-sum prefix (computed in-wave, nb<=64) and inits cursor
__global__ void scan_fixup(int* __restrict__ row_ptr, const int* __restrict__ bsum,
                           int nb, int N, int E, int* __restrict__ cursor) {
    __shared__ int pref[64];
    int t = threadIdx.x;
    if (t < 64) {
        int raw = (t < nb) ? bsum[t] : 0;
        int v = raw;
#pragma unroll
        for (int o = 1; o < 64; o <<= 1) {
            int u = __shfl_up(v, o, 64);
            if (t >= o) v += u;
        }
        pref[t] = v - raw;     // exclusive prefix
    }
    __syncthreads();
    int i = blockIdx.x * blockDim.x + t;
    if (i < N) { int val = row_ptr[i] + pref[i >> 10]; row_ptr[i] = val; cursor[i] = val; }
    if (i == 0) row_ptr[N] = E;
}

// pack (etype, src) into one int: src < 65536
__global__ void scatter_dst(const int* __restrict__ dst, const int* __restrict__ src,
                            const int* __restrict__ et, const float* __restrict__ norm,
                            int E, int* __restrict__ cursor, int2* __restrict__ edata) {
    int i = blockIdx.x * blockDim.x + threadIdx.x;
    if (i >= E) return;
    int p = atomicAdd(&cursor[dst[i]], 1);
    edata[p] = make_int2((et[i] << 16) | src[i], __float_as_int(norm[i]));
}

// ---------------- fused per-tile RGCN layer ----------------
// Block = 32 dst rows, 512 threads (8 waves). Phase A (quarter-wave row-parallel):
// quarter q of wave w owns dst row 4w+q; its 16 lanes cover that row's 128 cols as
// dwordx4 (lane l16 -> words 4*l16..4*l16+3). ONE gather instruction therefore carries
// 4 edges (one per quarter) -- 4x fewer serial round-trips than per-edge gathering,
// robust against compiler rescheduling (width, not depth). Trip count = max quad row
// length; idle slots gather a clamped-valid edge with nv=0. edata prefetched 2-deep
// via named ping-pong regs (no array copies -> no forced vmcnt drain). coef in LDS
// (per-quarter et), read as 2x ds_read_b128. Flush: no cross-lane reduce -- lane
// (q,l16) writes frag words Zs[b][l16>>2][l16&3][4w+q][0..3] (identical layout to the
// per-edge version; word w=4*l16+c -> kk=w>>4, lq=(w>>2)&3, ju=w&3).
// Phase B: Z(32x1024) @ V(1024x128); B-frags from L2-resident Vf; wave = t-tile x 2 m.
// mode 0: store bf16(relu(acc+bias)); mode 1: store fp32(acc+bias).

__global__ __launch_bounds__(512, 4) void rgcn_tile(
    const unsigned* __restrict__ hb, const int2* __restrict__ edata,
    const int* __restrict__ row_ptr, const float* __restrict__ coef,
    const short* __restrict__ Vf, const float* __restrict__ bias,
    void* __restrict__ outp, int N, int E, int mode) {
    __shared__ __align__(16) unsigned Zs[N_BASES][4][4][ROWS + 1][4];  // 66 KB
    __shared__ __align__(16) float cofs[N_RELS * N_BASES];             // 512 B

    const int tid = threadIdx.x;
    const int wave = tid >> 6, lane = tid & 63;
    const int l16 = lane & 15;
    const int nb0 = blockIdx.x * ROWS;

    if (tid < N_RELS * N_BASES) cofs[tid] = coef[tid];
    __syncthreads();

    // per-lane row bounds: quarter q handles local row r = tid>>4 (= wave*4 + q)
    const int r = tid >> 4;
    const int node = nb0 + (r & 31);
    const int cn = (node < N) ? node : (N - 1);
    const int s = row_ptr[cn];
    const int t = row_ptr[cn + 1];
    const int len = (node < N) ? (t - s) : 0;

    // wave-uniform trip count = max len over the wave's 4 quarters
    int mx = len;
    mx = max(mx, __shfl_xor(mx, 16, 64));
    mx = max(mx, __shfl_xor(mx, 32, 64));
    const int nG = __builtin_amdgcn_readfirstlane(mx);

    floatx2 acc[4][N_BASES] = {};   // [word c][base b], statically indexed only

    auto edix = [&](int j) { int ix = s + j; return (ix > E - 1) ? (E - 1) : ix; };
    auto gath = [&](int2 m) {
        return ((const uint4*)(hb + (size_t)(m.x & 0xffff) * 64))[l16];
    };
    auto procG = [&](int2 m, uint4 g, int j) {
        float nv = (j < len) ? __int_as_float(m.y) : 0.f;
        int ets = m.x >> 16;                               // always valid 0..15
        floatx4 c0 = *(const floatx4*)&cofs[ets * 8];      // ds_read_b128 x2
        floatx4 c1 = *(const floatx4*)&cofs[ets * 8 + 4];
        floatx2 v0, v1, v2, v3;
        v0.x = __uint_as_float(g.x << 16) * nv; v0.y = __uint_as_float(g.x & 0xffff0000u) * nv;
        v1.x = __uint_as_float(g.y << 16) * nv; v1.y = __uint_as_float(g.y & 0xffff0000u) * nv;
        v2.x = __uint_as_float(g.z << 16) * nv; v2.y = __uint_as_float(g.z & 0xffff0000u) * nv;
        v3.x = __uint_as_float(g.w << 16) * nv; v3.y = __uint_as_float(g.w & 0xffff0000u) * nv;
#pragma unroll
        for (int b = 0; b < N_BASES; b++) {
            float cw = (b < 4) ? c0[b & 3] : c1[b & 3];
            acc[0][b] = v0 * cw + acc[0][b];
            acc[1][b] = v1 * cw + acc[1][b];
            acc[2][b] = v2 * cw + acc[2][b];
            acc[3][b] = v3 * cw + acc[3][b];
        }
    };

    // 2-deep ping-pong: named regs only (register-array copies force vmcnt drains)
    int2 m0 = edata[edix(0)];
    uint4 g0 = gath(m0);
    int2 m1 = edata[edix(1)];

    int k = 0;
    for (; k + 2 <= nG; k += 2) {
        uint4 g1 = gath(m1);          // gather k+1 (m1 loaded >=1 iter ago)
        procG(m0, g0, k);             // waits g0 only (older in FIFO)
        m0 = edata[edix(k + 2)];
        g0 = gath(m0);                // gather k+2
        procG(m1, g1, k + 1);
        m1 = edata[edix(k + 3)];
    }
    if (k < nG) procG(m0, g0, k);     // nG-k <= 1

    // flush: lane (q,l16) owns row r, words 4*l16+c -> frag coords ((l16>>2),(l16&3),c)
    {
        uint4 w;
#pragma unroll
        for (int b = 0; b < N_BASES; b++) {
            w.x = packbf2(acc[0][b]);
            w.y = packbf2(acc[1][b]);
            w.z = packbf2(acc[2][b]);
            w.w = packbf2(acc[3][b]);
            *(uint4*)&Zs[b][l16 >> 2][l16 & 3][r & 31][0] = w;
        }
    }
    __syncthreads();

    // ---- phase B: wave owns t-tile tt=wave, m-tiles {0,1}
    const int q = lane >> 4, cc = lane & 15;
    const int tt = wave;
    floatx4 ac0 = {}, ac1 = {};

#pragma unroll 2
    for (int b = 0; b < N_BASES; b++) {
#pragma unroll
        for (int kk = 0; kk < 4; kk++) {
            bf16x8 a0 = *(const bf16x8*)&Zs[b][kk][q][cc][0];
            bf16x8 a1 = *(const bf16x8*)&Zs[b][kk][q][16 + cc][0];
            bf16x8 B = *(const bf16x8*)(Vf + (size_t)b * 16384 +
                                        ((size_t)(kk * 8 + tt) * 64 + lane) * 8);
            ac0 = __builtin_amdgcn_mfma_f32_16x16x32_bf16(a0, B, ac0, 0, 0, 0);
            ac1 = __builtin_amdgcn_mfma_f32_16x16x32_bf16(a1, B, ac1, 0, 0, 0);
        }
    }

    // ---- epilogue: C/D layout col = tt*16+cc, row(m) = mi*16 + q*4+i
    float bv = bias[tt * 16 + cc];
    if (mode == 0) {
        unsigned short* o = (unsigned short*)outp;
#pragma unroll
        for (int mi = 0; mi < 2; mi++) {
            const floatx4& c = mi ? ac1 : ac0;
#pragma unroll
            for (int i = 0; i < 4; i++) {
                int nd = nb0 + mi * 16 + q * 4 + i;
                if (nd < N) {
                    float v = fmaxf(c[i] + bv, 0.f);
                    o[(size_t)nd * HD + tt * 16 + cc] = (unsigned short)bf16rn(v);
                }
            }
        }
    } else {
        float* o = (float*)outp;
#pragma unroll
        for (int mi = 0; mi < 2; mi++) {
            const floatx4& c = mi ? ac1 : ac0;
#pragma unroll
            for (int i = 0; i < 4; i++) {
                int nd = nb0 + mi * 16 + q * 4 + i;
                if (nd < N) o[(size_t)nd * HD + tt * 16 + cc] = c[i] + bv;
            }
        }
    }
}

// ---------------- launch ----------------

extern "C" void kernel_launch(void* const* d_in, const int* in_sizes, int n_in,
                              void* d_out, int out_size, void* d_ws, size_t ws_size,
                              hipStream_t stream) {
    const float* h     = (const float*)d_in[0];
    const float* norm  = (const float*)d_in[1];
    const int*   src   = (const int*)d_in[2];
    const int*   dst   = (const int*)d_in[3];
    const int*   etype = (const int*)d_in[4];
    const float* V1    = (const float*)d_in[5];
    const float* coef1 = (const float*)d_in[6];
    const float* bias1 = (const float*)d_in[7];
    const float* V2    = (const float*)d_in[8];
    const float* coef2 = (const float*)d_in[9];
    const float* bias2 = (const float*)d_in[10];
    const int N = in_sizes[0] / HD;   // 50000
    const int E = in_sizes[2];        // 640000
    float* out = (float*)d_out;
    (void)n_in; (void)out_size; (void)ws_size;

    char* ws = (char*)d_ws;
    size_t off = 0;
    auto alloc = [&](size_t bytes) {
        void* p = ws + off;
        off += (bytes + 255) & ~(size_t)255;
        return p;
    };
    short*    Vf      = (short*)alloc((size_t)16 * 16384 * sizeof(short));   // 512 KB
    unsigned* hb      = (unsigned*)alloc((size_t)N * 64 * sizeof(unsigned)); // 12.8 MB
    unsigned* h1b     = (unsigned*)alloc((size_t)N * 64 * sizeof(unsigned)); // 12.8 MB
    int2*     edata   = (int2*)alloc((size_t)E * sizeof(int2));
    int*      cnt     = (int*)alloc((size_t)N * sizeof(int));
    int*      row_ptr = (int*)alloc((size_t)(N + 1) * sizeof(int));
    int*      cursor  = (int*)alloc((size_t)N * sizeof(int));
    int*      bsum    = (int*)alloc(256 * sizeof(int));

    const int nb = (N + SCAN_B - 1) / SCAN_B;                 // 49
    const int packBlocks = (N * 32 + 255) / 256;              // 6250 (float4 pack)
    const int vBlocks = 16;
    const int histBlocks = (E + 255) / 256;                   // 2500

    hipMemsetAsync(cnt, 0, (size_t)N * sizeof(int), stream);
    setup_fused<<<packBlocks + vBlocks + histBlocks, 256, 0, stream>>>(
        h, hb, N * 32, V1, V2, Vf, dst, E, cnt, packBlocks, vBlocks);
    scan_partial<<<nb, SCAN_B, 0, stream>>>(cnt, N, row_ptr, bsum);
    scan_fixup<<<(N + 255) / 256, 256, 0, stream>>>(row_ptr, bsum, nb, N, E, cursor);
    scatter_dst<<<(E + 255) / 256, 256, 0, stream>>>(dst, src, etype, norm, E, cursor, edata);

    const int tiles = (N + ROWS - 1) / ROWS;   // 1563

    // layer 1: h1b = bf16(relu(bias1 + Z @ V1))
    rgcn_tile<<<tiles, 512, 0, stream>>>(hb, edata, row_ptr, coef1, Vf, bias1, h1b, N, E, 0);
    // layer 2: out = bias2 + Z(h1b) @ V2
    rgcn_tile<<<tiles, 512, 0, stream>>>(h1b, edata, row_ptr, coef2, Vf + (size_t)8 * 16384,
                                         bias2, out, N, E, 1);
}